// Round 1
// baseline (227.073 us; speedup 1.0000x reference)
//
#include <hip/hip_runtime.h>

#define I_TOTAL 100000
#define DIM 64
#define BS 256

typedef __attribute__((ext_vector_type(8))) short bf16x8;
typedef __attribute__((ext_vector_type(4))) float f32x4;

__device__ inline unsigned short f2bf(float x) {
    union { float f; unsigned u; } v; v.f = x;
    return (unsigned short)((v.u + 0x8000u) >> 16);   // round-half-up to bf16
}

// Build M[n][d] (bf16), n = c*256 + b (c-major), M = u[b,:] * W[c,:] * log2(e)
__global__ __launch_bounds__(256) void prep_M(
    const int* __restrict__ bu, const float* __restrict__ ut,
    const float* __restrict__ cw, unsigned short* __restrict__ Mbf)
{
    int idx = blockIdx.x * 256 + threadIdx.x;   // 20480 threads, 4 d each
    int d = (idx & 15) * 4;
    int n = idx >> 4;                           // 0..1279
    int c = n >> 8, b = n & 255;
    const float s = 1.4426950408889634f;        // log2(e)
    float4 u = *(const float4*)(ut + (long)bu[b] * DIM + d);
    float4 w = *(const float4*)(cw + c * DIM + d);
    ushort4 r;
    r.x = f2bf(u.x * w.x * s);
    r.y = f2bf(u.y * w.y * s);
    r.z = f2bf(u.z * w.z * s);
    r.w = f2bf(u.w * w.w * s);
    *(ushort4*)(Mbf + n * DIM + d) = r;
}

// grid = (16 b-groups fast, 391 i-groups). Block = 256 (4 waves).
// Workgroup: 16 b x 256 i. Wave: 16 b x 64 i, 5 classes in 5x4 acc frags.
__global__ __launch_bounds__(256) void gemm_softmax(
    const float* __restrict__ item, const unsigned short* __restrict__ Mbf,
    const float* __restrict__ clsb, const float* __restrict__ vals,
    float* __restrict__ out)
{
    const int lane = threadIdx.x & 63;
    const int wave = threadIdx.x >> 6;
    const int col  = lane & 15;   // i within 16-tile (B/C col); m-row for A
    const int quad = lane >> 4;

    const int  b_base = blockIdx.x * 16;
    const long i_wave = (long)blockIdx.y * 256 + wave * 64;

    // A fragments: 5 classes x 2 K-halves, A[m=lane&15][k=quad*8+j]
    bf16x8 afr[5][2];
#pragma unroll
    for (int c = 0; c < 5; ++c) {
        const unsigned short* p = Mbf + (c * BS + b_base + col) * DIM + quad * 8;
        afr[c][0] = *(const bf16x8*)p;
        afr[c][1] = *(const bf16x8*)(p + 32);
    }

    f32x4 acc[5][4];
#pragma unroll
    for (int c = 0; c < 5; ++c)
#pragma unroll
        for (int t = 0; t < 4; ++t)
            acc[c][t] = (f32x4){0.f, 0.f, 0.f, 0.f};

#pragma unroll
    for (int t = 0; t < 4; ++t) {
        long i  = i_wave + t * 16 + col;
        long ic = (i < I_TOTAL) ? i : (I_TOTAL - 1);   // clamp loads, guard stores
        const float4* fp = (const float4*)(item + ic * DIM);
        float4 q0 = fp[2 * quad];         // k-half 0: d = quad*8 .. +7
        float4 q1 = fp[2 * quad + 1];
        float4 q2 = fp[8 + 2 * quad];     // k-half 1: d = 32 + quad*8 .. +7
        float4 q3 = fp[8 + 2 * quad + 1];
        bf16x8 b0, b1;
        b0[0] = (short)f2bf(q0.x); b0[1] = (short)f2bf(q0.y);
        b0[2] = (short)f2bf(q0.z); b0[3] = (short)f2bf(q0.w);
        b0[4] = (short)f2bf(q1.x); b0[5] = (short)f2bf(q1.y);
        b0[6] = (short)f2bf(q1.z); b0[7] = (short)f2bf(q1.w);
        b1[0] = (short)f2bf(q2.x); b1[1] = (short)f2bf(q2.y);
        b1[2] = (short)f2bf(q2.z); b1[3] = (short)f2bf(q2.w);
        b1[4] = (short)f2bf(q3.x); b1[5] = (short)f2bf(q3.y);
        b1[6] = (short)f2bf(q3.z); b1[7] = (short)f2bf(q3.w);
#pragma unroll
        for (int c = 0; c < 5; ++c) {
            acc[c][t] = __builtin_amdgcn_mfma_f32_16x16x32_bf16(afr[c][0], b0, acc[c][t], 0, 0, 0);
            acc[c][t] = __builtin_amdgcn_mfma_f32_16x16x32_bf16(afr[c][1], b1, acc[c][t], 0, 0, 0);
        }
    }

    // Epilogue: softmax over 5 classes entirely in-register (logits already *log2e)
    const float s = 1.4426950408889634f;
    float bb[5], vv[5];
#pragma unroll
    for (int c = 0; c < 5; ++c) { bb[c] = clsb[c] * s; vv[c] = vals[c]; }

#pragma unroll
    for (int t = 0; t < 4; ++t) {
        long i = i_wave + t * 16 + col;
        if (i >= I_TOTAL) continue;
#pragma unroll
        for (int r = 0; r < 4; ++r) {
            int b = b_base + quad * 4 + r;
            float num = 0.f, den = 0.f;
#pragma unroll
            for (int c = 0; c < 5; ++c) {
                float e = exp2f(acc[c][t][r] + bb[c]);
                den += e;
                num += e * vv[c];
            }
            out[(long)b * I_TOTAL + i] = num * __builtin_amdgcn_rcpf(den);
        }
    }
}

extern "C" void kernel_launch(void* const* d_in, const int* in_sizes, int n_in,
                              void* d_out, int out_size, void* d_ws, size_t ws_size,
                              hipStream_t stream) {
    const int*   bu   = (const int*)d_in[0];
    const float* ut   = (const float*)d_in[1];
    const float* it   = (const float*)d_in[2];
    const float* cw   = (const float*)d_in[3];
    const float* cb   = (const float*)d_in[4];
    const float* vals = (const float*)d_in[5];
    float* out = (float*)d_out;
    unsigned short* Mbf = (unsigned short*)d_ws;   // 1280*64*2 = 160 KB

    prep_M<<<80, 256, 0, stream>>>(bu, ut, cw, Mbf);
    dim3 grid(16, 391);   // b-groups fast (L2/L3 locality on item), ceil(100000/256)=391
    gemm_softmax<<<grid, 256, 0, stream>>>(it, Mbf, cb, vals, out);
}

// Round 2
// 192.199 us; speedup vs baseline: 1.1814x; 1.1814x over previous
//
#include <hip/hip_runtime.h>

#define I_TOTAL 100000
#define DIM 64
#define BS 256

typedef __attribute__((ext_vector_type(8))) short bf16x8;
typedef __attribute__((ext_vector_type(4))) float f32x4;

__device__ inline unsigned short f2bf(float x) {
    union { float f; unsigned u; } v; v.f = x;
    return (unsigned short)((v.u + 0x8000u) >> 16);   // round-half-up to bf16
}

// Build M[n][d] (bf16), n = c*256 + b (c-major), M = u[b,:] * W[c,:] * log2(e)
__global__ __launch_bounds__(256) void prep_M(
    const int* __restrict__ bu, const float* __restrict__ ut,
    const float* __restrict__ cw, unsigned short* __restrict__ Mbf)
{
    int idx = blockIdx.x * 256 + threadIdx.x;   // 20480 threads, 4 d each
    int d = (idx & 15) * 4;
    int n = idx >> 4;                           // 0..1279
    int c = n >> 8, b = n & 255;
    const float s = 1.4426950408889634f;        // log2(e)
    float4 u = *(const float4*)(ut + (long)bu[b] * DIM + d);
    float4 w = *(const float4*)(cw + c * DIM + d);
    ushort4 r;
    r.x = f2bf(u.x * w.x * s);
    r.y = f2bf(u.y * w.y * s);
    r.z = f2bf(u.z * w.z * s);
    r.w = f2bf(u.w * w.w * s);
    *(ushort4*)(Mbf + n * DIM + d) = r;
}

// Convert item table fp32 -> bf16 once (BW-bound, ~6 us).
// 100000*64 = 6.4e6 floats; 8 per thread; 800000 threads = 3125 blocks.
__global__ __launch_bounds__(256) void conv_items(
    const float* __restrict__ item, unsigned short* __restrict__ itbf)
{
    long t = (long)blockIdx.x * 256 + threadIdx.x;   // 0..799999
    const float4* p = (const float4*)(item + t * 8);
    float4 a = p[0], b = p[1];
    ushort4 r0, r1;
    r0.x = f2bf(a.x); r0.y = f2bf(a.y); r0.z = f2bf(a.z); r0.w = f2bf(a.w);
    r1.x = f2bf(b.x); r1.y = f2bf(b.y); r1.z = f2bf(b.z); r1.w = f2bf(b.w);
    ushort4* q = (ushort4*)(itbf + t * 8);
    q[0] = r0; q[1] = r1;
}

// grid = (16 b-groups fast, 391 i-groups). Block = 256 (4 waves).
// Workgroup: 16 b x 256 i. Wave: 16 b x 64 i, 5 classes in 5x4 acc frags.
template <bool PRE>
__global__ __launch_bounds__(256) void gemm_softmax(
    const float* __restrict__ item, const unsigned short* __restrict__ itbf,
    const unsigned short* __restrict__ Mbf,
    const float* __restrict__ clsb, const float* __restrict__ vals,
    float* __restrict__ out)
{
    const int lane = threadIdx.x & 63;
    const int wave = threadIdx.x >> 6;
    const int col  = lane & 15;   // i within 16-tile (B/C col); m-row for A
    const int quad = lane >> 4;

    const int  b_base = blockIdx.x * 16;
    const long i_wave = (long)blockIdx.y * 256 + wave * 64;

    // A fragments: 5 classes x 2 K-halves, A[m=lane&15][k=quad*8+j]
    bf16x8 afr[5][2];
#pragma unroll
    for (int c = 0; c < 5; ++c) {
        const unsigned short* p = Mbf + (c * BS + b_base + col) * DIM + quad * 8;
        afr[c][0] = *(const bf16x8*)p;
        afr[c][1] = *(const bf16x8*)(p + 32);
    }

    f32x4 acc[5][4];
#pragma unroll
    for (int c = 0; c < 5; ++c)
#pragma unroll
        for (int t = 0; t < 4; ++t)
            acc[c][t] = (f32x4){0.f, 0.f, 0.f, 0.f};

#pragma unroll
    for (int t = 0; t < 4; ++t) {
        long i  = i_wave + t * 16 + col;
        long ic = (i < I_TOTAL) ? i : (I_TOTAL - 1);   // clamp loads, guard stores
        bf16x8 b0, b1;
        if constexpr (PRE) {
            const unsigned short* rp = itbf + ic * DIM + quad * 8;
            b0 = *(const bf16x8*)rp;          // k-half 0: d = quad*8 .. +7
            b1 = *(const bf16x8*)(rp + 32);   // k-half 1: d = 32 + quad*8 .. +7
        } else {
            const float4* fp = (const float4*)(item + ic * DIM);
            float4 q0 = fp[2 * quad];
            float4 q1 = fp[2 * quad + 1];
            float4 q2 = fp[8 + 2 * quad];
            float4 q3 = fp[8 + 2 * quad + 1];
            b0[0] = (short)f2bf(q0.x); b0[1] = (short)f2bf(q0.y);
            b0[2] = (short)f2bf(q0.z); b0[3] = (short)f2bf(q0.w);
            b0[4] = (short)f2bf(q1.x); b0[5] = (short)f2bf(q1.y);
            b0[6] = (short)f2bf(q1.z); b0[7] = (short)f2bf(q1.w);
            b1[0] = (short)f2bf(q2.x); b1[1] = (short)f2bf(q2.y);
            b1[2] = (short)f2bf(q2.z); b1[3] = (short)f2bf(q2.w);
            b1[4] = (short)f2bf(q3.x); b1[5] = (short)f2bf(q3.y);
            b1[6] = (short)f2bf(q3.z); b1[7] = (short)f2bf(q3.w);
        }
#pragma unroll
        for (int c = 0; c < 5; ++c) {
            acc[c][t] = __builtin_amdgcn_mfma_f32_16x16x32_bf16(afr[c][0], b0, acc[c][t], 0, 0, 0);
            acc[c][t] = __builtin_amdgcn_mfma_f32_16x16x32_bf16(afr[c][1], b1, acc[c][t], 0, 0, 0);
        }
    }

    // Epilogue: softmax over 5 classes entirely in-register (logits already *log2e)
    const float s = 1.4426950408889634f;
    float bb[5], vv[5];
#pragma unroll
    for (int c = 0; c < 5; ++c) { bb[c] = clsb[c] * s; vv[c] = vals[c]; }

#pragma unroll
    for (int t = 0; t < 4; ++t) {
        long i = i_wave + t * 16 + col;
        if (i >= I_TOTAL) continue;
#pragma unroll
        for (int r = 0; r < 4; ++r) {
            int b = b_base + quad * 4 + r;
            float num = 0.f, den = 0.f;
#pragma unroll
            for (int c = 0; c < 5; ++c) {
                float e = exp2f(acc[c][t][r] + bb[c]);
                den += e;
                num += e * vv[c];
            }
            out[(long)b * I_TOTAL + i] = num * __builtin_amdgcn_rcpf(den);
        }
    }
}

extern "C" void kernel_launch(void* const* d_in, const int* in_sizes, int n_in,
                              void* d_out, int out_size, void* d_ws, size_t ws_size,
                              hipStream_t stream) {
    const int*   bu   = (const int*)d_in[0];
    const float* ut   = (const float*)d_in[1];
    const float* it   = (const float*)d_in[2];
    const float* cw   = (const float*)d_in[3];
    const float* cb   = (const float*)d_in[4];
    const float* vals = (const float*)d_in[5];
    float* out = (float*)d_out;
    unsigned short* Mbf = (unsigned short*)d_ws;              // 160 KB
    unsigned short* itbf = (unsigned short*)((char*)d_ws + 163840);  // 12.8 MB

    const size_t needed = 163840 + (size_t)I_TOTAL * DIM * 2;

    prep_M<<<80, 256, 0, stream>>>(bu, ut, cw, Mbf);
    dim3 grid(16, 391);   // b-groups fast (L2/L3 locality on item), ceil(100000/256)=391
    if (ws_size >= needed) {
        conv_items<<<3125, 256, 0, stream>>>(it, itbf);
        gemm_softmax<true><<<grid, 256, 0, stream>>>(it, itbf, Mbf, cb, vals, out);
    } else {
        gemm_softmax<false><<<grid, 256, 0, stream>>>(it, itbf, Mbf, cb, vals, out);
    }
}

// Round 3
// 187.099 us; speedup vs baseline: 1.2137x; 1.0273x over previous
//
#include <hip/hip_runtime.h>

#define I_TOTAL 100000
#define DIM 64
#define BS 256

typedef __attribute__((ext_vector_type(8))) short bf16x8;
typedef __attribute__((ext_vector_type(4))) float f32x4;

__device__ inline unsigned short f2bf(float x) {
    union { float f; unsigned u; } v; v.f = x;
    return (unsigned short)((v.u + 0x8000u) >> 16);   // round-half-up to bf16
}

// Build M[n][d] (bf16), n = c*256 + b (c-major), M = u[b,:] * W[c,:] * log2(e)
__global__ __launch_bounds__(256) void prep_M(
    const int* __restrict__ bu, const float* __restrict__ ut,
    const float* __restrict__ cw, unsigned short* __restrict__ Mbf)
{
    int idx = blockIdx.x * 256 + threadIdx.x;   // 20480 threads, 4 d each
    int d = (idx & 15) * 4;
    int n = idx >> 4;                           // 0..1279
    int c = n >> 8, b = n & 255;
    const float s = 1.4426950408889634f;        // log2(e)
    float4 u = *(const float4*)(ut + (long)bu[b] * DIM + d);
    float4 w = *(const float4*)(cw + c * DIM + d);
    ushort4 r;
    r.x = f2bf(u.x * w.x * s);
    r.y = f2bf(u.y * w.y * s);
    r.z = f2bf(u.z * w.z * s);
    r.w = f2bf(u.w * w.w * s);
    *(ushort4*)(Mbf + n * DIM + d) = r;
}

// Convert item table fp32 -> bf16 once (BW-bound).
__global__ __launch_bounds__(256) void conv_items(
    const float* __restrict__ item, unsigned short* __restrict__ itbf)
{
    long t = (long)blockIdx.x * 256 + threadIdx.x;   // 0..799999
    const float4* p = (const float4*)(item + t * 8);
    float4 a = p[0], b = p[1];
    ushort4 r0, r1;
    r0.x = f2bf(a.x); r0.y = f2bf(a.y); r0.z = f2bf(a.z); r0.w = f2bf(a.w);
    r1.x = f2bf(b.x); r1.y = f2bf(b.y); r1.z = f2bf(b.z); r1.w = f2bf(b.w);
    ushort4* q = (ushort4*)(itbf + t * 8);
    q[0] = r0; q[1] = r1;
}

// 1D grid of 1664 blocks (96 idle). Decode so all 16 b-group blocks of one
// i-range share blk%8 (same XCD under round-robin) -> itbf fetched ~once/XCD.
// Block: 16 b x 1024 i. Wave: 16 b x 256 i (16 tiles), 5 classes.
__global__ __launch_bounds__(256) void gemm_softmax(
    const unsigned short* __restrict__ itbf,
    const unsigned short* __restrict__ Mbf,
    const float* __restrict__ clsb, const float* __restrict__ vals,
    float* __restrict__ out)
{
    const int blk = blockIdx.x;
    const int r8 = blk & 7;
    const int q  = blk >> 3;
    const int g  = q & 15;          // b-group (16 b each)
    const int a  = q >> 4;          // 0..12
    const int y  = a * 8 + r8;      // i-range id, 0..103
    if (y >= 98) return;

    const int lane = threadIdx.x & 63;
    const int wave = threadIdx.x >> 6;
    const int col  = lane & 15;     // A m-row (b in group) / C col (i in tile)
    const int quad = lane >> 4;

    const int b_base = g * 16;
    const int i_base = y * 1024 + wave * 256;   // this wave's 16 i-tiles

    // A fragments: 5 classes x 2 K-halves, loaded ONCE per wave
    bf16x8 afr[5][2];
#pragma unroll
    for (int c = 0; c < 5; ++c) {
        const unsigned short* p = Mbf + (c * BS + b_base + col) * DIM + quad * 8;
        afr[c][0] = *(const bf16x8*)p;
        afr[c][1] = *(const bf16x8*)(p + 32);
    }

    const f32x4 zero = (f32x4){0.f, 0.f, 0.f, 0.f};

    const float s = 1.4426950408889634f;
    float bb[5], vv[5];
#pragma unroll
    for (int c = 0; c < 5; ++c) { bb[c] = clsb[c] * s; vv[c] = vals[c]; }

    if (y < 97) {
        // ---- fast path: no bounds checks ----
        // 4 row pointers, stores use compile-time immediate offsets
        float* op[4];
#pragma unroll
        for (int rr = 0; rr < 4; ++rr)
            op[rr] = out + (size_t)(b_base + quad * 4 + rr) * I_TOTAL + (i_base + col);

        const unsigned short* bp = itbf + (size_t)(i_base + col) * DIM + quad * 8;

#pragma unroll 1
        for (int t4 = 0; t4 < 4; ++t4) {
#pragma unroll
            for (int ti = 0; ti < 4; ++ti) {
                bf16x8 b0 = *(const bf16x8*)(bp + ti * 1024);
                bf16x8 b1 = *(const bf16x8*)(bp + ti * 1024 + 32);
                f32x4 acc[5];
#pragma unroll
                for (int c = 0; c < 5; ++c) {
                    acc[c] = __builtin_amdgcn_mfma_f32_16x16x32_bf16(afr[c][0], b0, zero, 0, 0, 0);
                    acc[c] = __builtin_amdgcn_mfma_f32_16x16x32_bf16(afr[c][1], b1, acc[c], 0, 0, 0);
                }
#pragma unroll
                for (int rr = 0; rr < 4; ++rr) {
                    float e0 = exp2f(acc[0][rr] + bb[0]);
                    float e1 = exp2f(acc[1][rr] + bb[1]);
                    float e2 = exp2f(acc[2][rr] + bb[2]);
                    float e3 = exp2f(acc[3][rr] + bb[3]);
                    float e4 = exp2f(acc[4][rr] + bb[4]);
                    float den = ((e0 + e1) + (e2 + e3)) + e4;
                    float num = e0 * vv[0];
                    num = fmaf(e1, vv[1], num);
                    num = fmaf(e2, vv[2], num);
                    num = fmaf(e3, vv[3], num);
                    num = fmaf(e4, vv[4], num);
                    op[rr][ti * 16] = num * __builtin_amdgcn_rcpf(den);
                }
            }
            bp += 4 * 1024;             // 4 tiles * 16 rows * 64 shorts
#pragma unroll
            for (int rr = 0; rr < 4; ++rr) op[rr] += 64;
        }
    } else {
        // ---- tail path (y == 97): clamp loads, guard stores ----
#pragma unroll 1
        for (int t = 0; t < 16; ++t) {
            int i  = i_base + t * 16 + col;
            int ic = i < I_TOTAL ? i : I_TOTAL - 1;
            const unsigned short* p2 = itbf + (size_t)ic * DIM + quad * 8;
            bf16x8 b0 = *(const bf16x8*)p2;
            bf16x8 b1 = *(const bf16x8*)(p2 + 32);
            f32x4 acc[5];
#pragma unroll
            for (int c = 0; c < 5; ++c) {
                acc[c] = __builtin_amdgcn_mfma_f32_16x16x32_bf16(afr[c][0], b0, zero, 0, 0, 0);
                acc[c] = __builtin_amdgcn_mfma_f32_16x16x32_bf16(afr[c][1], b1, acc[c], 0, 0, 0);
            }
            if (i < I_TOTAL) {
#pragma unroll
                for (int rr = 0; rr < 4; ++rr) {
                    float e0 = exp2f(acc[0][rr] + bb[0]);
                    float e1 = exp2f(acc[1][rr] + bb[1]);
                    float e2 = exp2f(acc[2][rr] + bb[2]);
                    float e3 = exp2f(acc[3][rr] + bb[3]);
                    float e4 = exp2f(acc[4][rr] + bb[4]);
                    float den = ((e0 + e1) + (e2 + e3)) + e4;
                    float num = e0 * vv[0];
                    num = fmaf(e1, vv[1], num);
                    num = fmaf(e2, vv[2], num);
                    num = fmaf(e3, vv[3], num);
                    num = fmaf(e4, vv[4], num);
                    out[(size_t)(b_base + quad * 4 + rr) * I_TOTAL + i] =
                        num * __builtin_amdgcn_rcpf(den);
                }
            }
        }
    }
}

// Fallback (no workspace for bf16 items): inline-convert variant (R1 logic).
__global__ __launch_bounds__(256) void gemm_softmax_fb(
    const float* __restrict__ item, const unsigned short* __restrict__ Mbf,
    const float* __restrict__ clsb, const float* __restrict__ vals,
    float* __restrict__ out)
{
    const int lane = threadIdx.x & 63;
    const int wave = threadIdx.x >> 6;
    const int col  = lane & 15;
    const int quad = lane >> 4;
    const int  b_base = blockIdx.x * 16;
    const long i_wave = (long)blockIdx.y * 256 + wave * 64;

    bf16x8 afr[5][2];
#pragma unroll
    for (int c = 0; c < 5; ++c) {
        const unsigned short* p = Mbf + (c * BS + b_base + col) * DIM + quad * 8;
        afr[c][0] = *(const bf16x8*)p;
        afr[c][1] = *(const bf16x8*)(p + 32);
    }
    f32x4 acc[5][4];
#pragma unroll
    for (int c = 0; c < 5; ++c)
#pragma unroll
        for (int t = 0; t < 4; ++t) acc[c][t] = (f32x4){0.f,0.f,0.f,0.f};
#pragma unroll
    for (int t = 0; t < 4; ++t) {
        long i  = i_wave + t * 16 + col;
        long ic = (i < I_TOTAL) ? i : (I_TOTAL - 1);
        const float4* fp = (const float4*)(item + ic * DIM);
        float4 q0 = fp[2*quad], q1 = fp[2*quad+1], q2 = fp[8+2*quad], q3 = fp[8+2*quad+1];
        bf16x8 b0, b1;
        b0[0]=(short)f2bf(q0.x); b0[1]=(short)f2bf(q0.y); b0[2]=(short)f2bf(q0.z); b0[3]=(short)f2bf(q0.w);
        b0[4]=(short)f2bf(q1.x); b0[5]=(short)f2bf(q1.y); b0[6]=(short)f2bf(q1.z); b0[7]=(short)f2bf(q1.w);
        b1[0]=(short)f2bf(q2.x); b1[1]=(short)f2bf(q2.y); b1[2]=(short)f2bf(q2.z); b1[3]=(short)f2bf(q2.w);
        b1[4]=(short)f2bf(q3.x); b1[5]=(short)f2bf(q3.y); b1[6]=(short)f2bf(q3.z); b1[7]=(short)f2bf(q3.w);
#pragma unroll
        for (int c = 0; c < 5; ++c) {
            acc[c][t] = __builtin_amdgcn_mfma_f32_16x16x32_bf16(afr[c][0], b0, acc[c][t], 0, 0, 0);
            acc[c][t] = __builtin_amdgcn_mfma_f32_16x16x32_bf16(afr[c][1], b1, acc[c][t], 0, 0, 0);
        }
    }
    const float s = 1.4426950408889634f;
    float bb[5], vv[5];
#pragma unroll
    for (int c = 0; c < 5; ++c) { bb[c] = clsb[c] * s; vv[c] = vals[c]; }
#pragma unroll
    for (int t = 0; t < 4; ++t) {
        long i = i_wave + t * 16 + col;
        if (i >= I_TOTAL) continue;
#pragma unroll
        for (int r = 0; r < 4; ++r) {
            int b = b_base + quad * 4 + r;
            float num = 0.f, den = 0.f;
#pragma unroll
            for (int c = 0; c < 5; ++c) {
                float e = exp2f(acc[c][t][r] + bb[c]);
                den += e; num = fmaf(e, vv[c], num);
            }
            out[(long)b * I_TOTAL + i] = num * __builtin_amdgcn_rcpf(den);
        }
    }
}

extern "C" void kernel_launch(void* const* d_in, const int* in_sizes, int n_in,
                              void* d_out, int out_size, void* d_ws, size_t ws_size,
                              hipStream_t stream) {
    const int*   bu   = (const int*)d_in[0];
    const float* ut   = (const float*)d_in[1];
    const float* it   = (const float*)d_in[2];
    const float* cw   = (const float*)d_in[3];
    const float* cb   = (const float*)d_in[4];
    const float* vals = (const float*)d_in[5];
    float* out = (float*)d_out;
    unsigned short* Mbf  = (unsigned short*)d_ws;                    // 160 KB
    unsigned short* itbf = (unsigned short*)((char*)d_ws + 163840);  // 12.8 MB

    const size_t needed = 163840 + (size_t)I_TOTAL * DIM * 2;

    prep_M<<<80, 256, 0, stream>>>(bu, ut, cw, Mbf);
    if (ws_size >= needed) {
        conv_items<<<3125, 256, 0, stream>>>(it, itbf);
        gemm_softmax<<<1664, 256, 0, stream>>>(itbf, Mbf, cb, vals, out);
    } else {
        dim3 grid(16, 391);
        gemm_softmax_fb<<<grid, 256, 0, stream>>>(it, Mbf, cb, vals, out);
    }
}

// Round 4
// 177.685 us; speedup vs baseline: 1.2780x; 1.0530x over previous
//
#include <hip/hip_runtime.h>

#define I_TOTAL 100000
#define DIM 64
#define BS 256

typedef __attribute__((ext_vector_type(8))) short bf16x8;
typedef __attribute__((ext_vector_type(4))) float f32x4;

__device__ inline unsigned short f2bf(float x) {
    union { float f; unsigned u; } v; v.f = x;
    return (unsigned short)((v.u + 0x8000u) >> 16);   // round-half-up to bf16
}

// Build M[n][d] (bf16), n = c*256 + b (c-major), M = u[b,:] * W[c,:] * log2(e)
__global__ __launch_bounds__(256) void prep_M(
    const int* __restrict__ bu, const float* __restrict__ ut,
    const float* __restrict__ cw, unsigned short* __restrict__ Mbf)
{
    int idx = blockIdx.x * 256 + threadIdx.x;
    int d = (idx & 15) * 4;
    int n = idx >> 4;                           // 0..1279
    int c = n >> 8, b = n & 255;
    const float s = 1.4426950408889634f;        // log2(e)
    float4 u = *(const float4*)(ut + (long)bu[b] * DIM + d);
    float4 w = *(const float4*)(cw + c * DIM + d);
    ushort4 r;
    r.x = f2bf(u.x * w.x * s);
    r.y = f2bf(u.y * w.y * s);
    r.z = f2bf(u.z * w.z * s);
    r.w = f2bf(u.w * w.w * s);
    *(ushort4*)(Mbf + n * DIM + d) = r;
}

// Convert item table fp32 -> bf16 once (BW-bound).
__global__ __launch_bounds__(256) void conv_items(
    const float* __restrict__ item, unsigned short* __restrict__ itbf)
{
    long t = (long)blockIdx.x * 256 + threadIdx.x;   // 0..799999
    const float4* p = (const float4*)(item + t * 8);
    float4 a = p[0], b = p[1];
    ushort4 r0, r1;
    r0.x = f2bf(a.x); r0.y = f2bf(a.y); r0.z = f2bf(a.z); r0.w = f2bf(a.w);
    r1.x = f2bf(b.x); r1.y = f2bf(b.y); r1.z = f2bf(b.z); r1.w = f2bf(b.w);
    ushort4* q = (ushort4*)(itbf + t * 8);
    q[0] = r0; q[1] = r1;
}

// 1D grid of 1664 blocks (96 idle). blk%8 keyed to i-range -> same XCD reads
// the same itbf slice (FETCH ~8 MB, verified R3).
// Block: 16 b x 1024 i. Wave: 16 b x 256 i (16 tiles), 5 classes.
__global__ __launch_bounds__(256) void gemm_softmax(
    const unsigned short* __restrict__ itbf,
    const unsigned short* __restrict__ Mbf,
    const float* __restrict__ clsb, const float* __restrict__ vals,
    float* __restrict__ out)
{
    // per-wave private transpose buffer: 4 waves * 1056 dw = 16896 B.
    // slot(dw) = wave*1056 + quad*264 + rr*64 + ti*16 + col   (264 = 8-dw skew
    // per quad -> all LDS ops <=2-way bank aliased = free)
    __shared__ float ldsb[4224];

    const int blk = blockIdx.x;
    const int r8 = blk & 7;
    const int q  = blk >> 3;
    const int g  = q & 15;          // b-group (16 b each)
    const int a  = q >> 4;          // 0..12
    const int y  = a * 8 + r8;      // i-range id, 0..103
    if (y >= 98) return;

    const int lane = threadIdx.x & 63;
    const int wave = threadIdx.x >> 6;
    const int col  = lane & 15;     // A m-row (b in group) / C col (i in tile)
    const int quad = lane >> 4;

    const int b_base = g * 16;
    const int i_base = y * 1024 + wave * 256;   // this wave's 16 i-tiles

    // A fragments: 5 classes x 2 K-halves, loaded ONCE per wave
    bf16x8 afr[5][2];
#pragma unroll
    for (int c = 0; c < 5; ++c) {
        const unsigned short* p = Mbf + (c * BS + b_base + col) * DIM + quad * 8;
        afr[c][0] = *(const bf16x8*)p;
        afr[c][1] = *(const bf16x8*)(p + 32);
    }

    const f32x4 zero = (f32x4){0.f, 0.f, 0.f, 0.f};
    const float s = 1.4426950408889634f;
    float bb[5], vv[5];
#pragma unroll
    for (int c = 0; c < 5; ++c) { bb[c] = clsb[c] * s; vv[c] = vals[c]; }

    if (y < 97) {
        // ---- fast path ----
        float* wlds = ldsb + wave * 1056 + quad * 264 + col;        // write base
        const float* rlds = ldsb + wave * 1056 + quad * 264 + 4 * col; // read base

        float* op[4];
#pragma unroll
        for (int k = 0; k < 4; ++k)
            op[k] = out + (size_t)(b_base + quad * 4 + k) * I_TOTAL + (i_base + 4 * col);

        const unsigned short* bp = itbf + (size_t)(i_base + col) * DIM + quad * 8;

#pragma unroll 1
        for (int t4 = 0; t4 < 4; ++t4) {
#pragma unroll
            for (int ti = 0; ti < 4; ++ti) {
                bf16x8 b0 = *(const bf16x8*)(bp + ti * 1024);
                bf16x8 b1 = *(const bf16x8*)(bp + ti * 1024 + 32);
                f32x4 acc[5];
#pragma unroll
                for (int c = 0; c < 5; ++c) {
                    acc[c] = __builtin_amdgcn_mfma_f32_16x16x32_bf16(afr[c][0], b0, zero, 0, 0, 0);
                    acc[c] = __builtin_amdgcn_mfma_f32_16x16x32_bf16(afr[c][1], b1, acc[c], 0, 0, 0);
                }
                // logits (pre-scaled by log2e); vector add -> v_pk_add_f32
                f32x4 l[5];
#pragma unroll
                for (int c = 0; c < 5; ++c) l[c] = acc[c] + bb[c];
#pragma unroll
                for (int rr = 0; rr < 4; ++rr) {
                    float e0 = __builtin_amdgcn_exp2f(l[0][rr]);
                    float e1 = __builtin_amdgcn_exp2f(l[1][rr]);
                    float e2 = __builtin_amdgcn_exp2f(l[2][rr]);
                    float e3 = __builtin_amdgcn_exp2f(l[3][rr]);
                    float e4 = __builtin_amdgcn_exp2f(l[4][rr]);
                    float den = ((e0 + e1) + (e2 + e3)) + e4;
                    float num = e0 * vv[0];
                    num = fmaf(e1, vv[1], num);
                    num = fmaf(e2, vv[2], num);
                    num = fmaf(e3, vv[3], num);
                    num = fmaf(e4, vv[4], num);
                    wlds[rr * 64 + ti * 16] = num * __builtin_amdgcn_rcpf(den);
                }
            }
            // transpose read-back: round k = b-row within quad; 1-KB wave stores
#pragma unroll
            for (int k = 0; k < 4; ++k) {
                f32x4 o4 = *(const f32x4*)(rlds + k * 64);
                *(f32x4*)op[k] = o4;
                op[k] += 64;
            }
            bp += 4 * 1024;
        }
    } else {
        // ---- tail path (y == 97): clamp loads, guard stores ----
#pragma unroll 1
        for (int t = 0; t < 16; ++t) {
            int i  = i_base + t * 16 + col;
            int ic = i < I_TOTAL ? i : I_TOTAL - 1;
            const unsigned short* p2 = itbf + (size_t)ic * DIM + quad * 8;
            bf16x8 b0 = *(const bf16x8*)p2;
            bf16x8 b1 = *(const bf16x8*)(p2 + 32);
            f32x4 acc[5];
#pragma unroll
            for (int c = 0; c < 5; ++c) {
                acc[c] = __builtin_amdgcn_mfma_f32_16x16x32_bf16(afr[c][0], b0, zero, 0, 0, 0);
                acc[c] = __builtin_amdgcn_mfma_f32_16x16x32_bf16(afr[c][1], b1, acc[c], 0, 0, 0);
            }
            if (i < I_TOTAL) {
#pragma unroll
                for (int rr = 0; rr < 4; ++rr) {
                    float e0 = __builtin_amdgcn_exp2f(acc[0][rr] + bb[0]);
                    float e1 = __builtin_amdgcn_exp2f(acc[1][rr] + bb[1]);
                    float e2 = __builtin_amdgcn_exp2f(acc[2][rr] + bb[2]);
                    float e3 = __builtin_amdgcn_exp2f(acc[3][rr] + bb[3]);
                    float e4 = __builtin_amdgcn_exp2f(acc[4][rr] + bb[4]);
                    float den = ((e0 + e1) + (e2 + e3)) + e4;
                    float num = e0 * vv[0];
                    num = fmaf(e1, vv[1], num);
                    num = fmaf(e2, vv[2], num);
                    num = fmaf(e3, vv[3], num);
                    num = fmaf(e4, vv[4], num);
                    out[(size_t)(b_base + quad * 4 + rr) * I_TOTAL + i] =
                        num * __builtin_amdgcn_rcpf(den);
                }
            }
        }
    }
}

// Fallback (no workspace for bf16 items): inline-convert variant.
__global__ __launch_bounds__(256) void gemm_softmax_fb(
    const float* __restrict__ item, const unsigned short* __restrict__ Mbf,
    const float* __restrict__ clsb, const float* __restrict__ vals,
    float* __restrict__ out)
{
    const int lane = threadIdx.x & 63;
    const int wave = threadIdx.x >> 6;
    const int col  = lane & 15;
    const int quad = lane >> 4;
    const int  b_base = blockIdx.x * 16;
    const long i_wave = (long)blockIdx.y * 256 + wave * 64;

    bf16x8 afr[5][2];
#pragma unroll
    for (int c = 0; c < 5; ++c) {
        const unsigned short* p = Mbf + (c * BS + b_base + col) * DIM + quad * 8;
        afr[c][0] = *(const bf16x8*)p;
        afr[c][1] = *(const bf16x8*)(p + 32);
    }
    f32x4 acc[5][4];
#pragma unroll
    for (int c = 0; c < 5; ++c)
#pragma unroll
        for (int t = 0; t < 4; ++t) acc[c][t] = (f32x4){0.f,0.f,0.f,0.f};
#pragma unroll
    for (int t = 0; t < 4; ++t) {
        long i  = i_wave + t * 16 + col;
        long ic = (i < I_TOTAL) ? i : (I_TOTAL - 1);
        const float4* fp = (const float4*)(item + ic * DIM);
        float4 q0 = fp[2*quad], q1 = fp[2*quad+1], q2 = fp[8+2*quad], q3 = fp[8+2*quad+1];
        bf16x8 b0, b1;
        b0[0]=(short)f2bf(q0.x); b0[1]=(short)f2bf(q0.y); b0[2]=(short)f2bf(q0.z); b0[3]=(short)f2bf(q0.w);
        b0[4]=(short)f2bf(q1.x); b0[5]=(short)f2bf(q1.y); b0[6]=(short)f2bf(q1.z); b0[7]=(short)f2bf(q1.w);
        b1[0]=(short)f2bf(q2.x); b1[1]=(short)f2bf(q2.y); b1[2]=(short)f2bf(q2.z); b1[3]=(short)f2bf(q2.w);
        b1[4]=(short)f2bf(q3.x); b1[5]=(short)f2bf(q3.y); b1[6]=(short)f2bf(q3.z); b1[7]=(short)f2bf(q3.w);
#pragma unroll
        for (int c = 0; c < 5; ++c) {
            acc[c][t] = __builtin_amdgcn_mfma_f32_16x16x32_bf16(afr[c][0], b0, acc[c][t], 0, 0, 0);
            acc[c][t] = __builtin_amdgcn_mfma_f32_16x16x32_bf16(afr[c][1], b1, acc[c][t], 0, 0, 0);
        }
    }
    const float s = 1.4426950408889634f;
    float bb[5], vv[5];
#pragma unroll
    for (int c = 0; c < 5; ++c) { bb[c] = clsb[c] * s; vv[c] = vals[c]; }
#pragma unroll
    for (int t = 0; t < 4; ++t) {
        long i = i_wave + t * 16 + col;
        if (i >= I_TOTAL) continue;
#pragma unroll
        for (int r = 0; r < 4; ++r) {
            int b = b_base + quad * 4 + r;
            float num = 0.f, den = 0.f;
#pragma unroll
            for (int c = 0; c < 5; ++c) {
                float e = __builtin_amdgcn_exp2f(acc[c][t][r] + bb[c]);
                den += e; num = fmaf(e, vv[c], num);
            }
            out[(long)b * I_TOTAL + i] = num * __builtin_amdgcn_rcpf(den);
        }
    }
}

extern "C" void kernel_launch(void* const* d_in, const int* in_sizes, int n_in,
                              void* d_out, int out_size, void* d_ws, size_t ws_size,
                              hipStream_t stream) {
    const int*   bu   = (const int*)d_in[0];
    const float* ut   = (const float*)d_in[1];
    const float* it   = (const float*)d_in[2];
    const float* cw   = (const float*)d_in[3];
    const float* cb   = (const float*)d_in[4];
    const float* vals = (const float*)d_in[5];
    float* out = (float*)d_out;
    unsigned short* Mbf  = (unsigned short*)d_ws;                    // 160 KB
    unsigned short* itbf = (unsigned short*)((char*)d_ws + 163840);  // 12.8 MB

    const size_t needed = 163840 + (size_t)I_TOTAL * DIM * 2;

    prep_M<<<80, 256, 0, stream>>>(bu, ut, cw, Mbf);
    if (ws_size >= needed) {
        conv_items<<<3125, 256, 0, stream>>>(it, itbf);
        gemm_softmax<<<1664, 256, 0, stream>>>(itbf, Mbf, cb, vals, out);
    } else {
        dim3 grid(16, 391);
        gemm_softmax_fb<<<grid, 256, 0, stream>>>(it, Mbf, cb, vals, out);
    }
}